// Round 10
// baseline (48.634 us; speedup 1.0000x reference)
//
#include <hip/hip_runtime.h>
#include <hip/hip_bf16.h>
#include <math.h>

#define NSENT 256
#define SLEN  512
#define VROWS 50000
#define EDIM  300
#define NROW  12
#define NSTEP 10              // ceil(300/32) K-steps of 16x16x32 MFMA
#define NTILE 3125            // 16-row MFMA tiles over the vocab (exact: 3125*16=50000)
#define CNT_OFF (8u << 20)    // barrier counter at +8MB in d_ws (s-table is 2.4MB)

typedef __attribute__((ext_vector_type(8))) short bf16x8;
typedef __attribute__((ext_vector_type(4))) float f32x4;

static __device__ __forceinline__ short f2bf(float f) {
    __hip_bfloat16 h = __float2bfloat16(f);   // RNE
    short s;
    __builtin_memcpy(&s, &h, sizeof(s));
    return s;
}

// ---------------------------------------------------------------------------
// Single fused kernel. 256 blocks x 256 thr (all co-resident: 256 blocks <=
// 256 CUs and each block uses <=1/4 CU resources -> hand-rolled device
// barrier cannot deadlock).
// Phase A (round-8 body): vocab scores via bf16 MFMA; 3125 16-row tiles
//   distributed per-wave (waves 0..52 take 4 tiles, rest 3) -> ~zero tail.
// Barrier: release fetch_add + acquire spin on a counter zeroed each call
//   by hipMemsetAsync (stateless across replays).
// Phase B: per-sentence gather from s-table + windows + tanh + max + fc +
//   log_softmax, 2 tokens per thread.
// ---------------------------------------------------------------------------
__global__ __launch_bounds__(256, 4)
void textcnn_fused(const int*   __restrict__ sent,
                   const float* __restrict__ emb,
                   const float* __restrict__ k3, const float* __restrict__ b3,
                   const float* __restrict__ k4, const float* __restrict__ b4,
                   const float* __restrict__ k5, const float* __restrict__ b5,
                   const float* __restrict__ fcw, const float* __restrict__ fcb,
                   float* __restrict__ out,
                   float* __restrict__ s,
                   unsigned int* __restrict__ cnt)
{
    __shared__ bf16x8 bfrag_lds[NSTEP * 64];   // 10.25 KB (phase A)
    __shared__ float  s_lds[NROW * SLEN];      // 24 KB   (phase B)
    __shared__ float  red[4][3];

    const int tid  = threadIdx.x;
    const int lane = tid & 63;
    const int wave = tid >> 6;      // 0..3
    const int rc   = lane & 15;     // A-row-in-tile / D-col (conv row)
    const int kg   = lane >> 4;     // k-group 0..3

    // ---- build B fragments cooperatively (weights tiny, L1/L2-hot) --------
    for (int e = tid; e < NSTEP * 64; e += 256) {
        const int st  = e >> 6;
        const int le  = e & 63;
        const int rce = le & 15;
        const int kge = le >> 4;
        const float* krow = nullptr;
        if      (rce < 3)  krow = k3 + rce * EDIM;
        else if (rce < 7)  krow = k4 + (rce - 3) * EDIM;
        else if (rce < 12) krow = k5 + (rce - 7) * EDIM;
        const int k0 = st * 32 + kge * 8;
        float4 b0 = make_float4(0.f,0.f,0.f,0.f);
        float4 b1 = make_float4(0.f,0.f,0.f,0.f);
        if (krow) {
            if (k0 + 4 <= EDIM) b0 = *reinterpret_cast<const float4*>(krow + k0);
            if (k0 + 8 <= EDIM) b1 = *reinterpret_cast<const float4*>(krow + k0 + 4);
        }
        bf16x8 f;
        f[0]=f2bf(b0.x); f[1]=f2bf(b0.y); f[2]=f2bf(b0.z); f[3]=f2bf(b0.w);
        f[4]=f2bf(b1.x); f[5]=f2bf(b1.y); f[6]=f2bf(b1.z); f[7]=f2bf(b1.w);
        bfrag_lds[e] = f;
    }
    __syncthreads();

    // ================= Phase A: vocab scores (per-wave tiles) ==============
    const int gw = blockIdx.x * 4 + wave;      // global wave id 0..1023
    int t0, nt;
    if (gw < 53) { t0 = gw * 4;      nt = 4; } // 53*4 = 212
    else         { t0 = gw * 3 + 53; nt = 3; } // 212 + (gw-53)*3
    for (int it = 0; it < nt; ++it) {
        const int vbase = (t0 + it) * 16;
        const float* arow = emb + (size_t)(vbase + rc) * EDIM;
        f32x4 acc = {0.f, 0.f, 0.f, 0.f};
        #pragma unroll
        for (int half = 0; half < 2; ++half) {
            float4 a0[5], a1[5];
            #pragma unroll
            for (int i = 0; i < 5; ++i) {
                const int k0 = (half * 5 + i) * 32 + kg * 8;
                a0[i] = (k0 + 4 <= EDIM)
                      ? *reinterpret_cast<const float4*>(arow + k0)
                      : make_float4(0.f,0.f,0.f,0.f);
                a1[i] = (k0 + 8 <= EDIM)
                      ? *reinterpret_cast<const float4*>(arow + k0 + 4)
                      : make_float4(0.f,0.f,0.f,0.f);
            }
            #pragma unroll
            for (int i = 0; i < 5; ++i) {
                const int st = half * 5 + i;
                const bf16x8 bf = bfrag_lds[st * 64 + lane];   // ds_read_b128
                bf16x8 af;
                af[0]=f2bf(a0[i].x); af[1]=f2bf(a0[i].y);
                af[2]=f2bf(a0[i].z); af[3]=f2bf(a0[i].w);
                af[4]=f2bf(a1[i].x); af[5]=f2bf(a1[i].y);
                af[6]=f2bf(a1[i].z); af[7]=f2bf(a1[i].w);
                acc = __builtin_amdgcn_mfma_f32_16x16x32_bf16(af, bf, acc, 0,0,0);
            }
        }
        if (rc < NROW) {
            #pragma unroll
            for (int j = 0; j < 4; ++j)
                s[(size_t)(vbase + kg * 4 + j) * NROW + rc] = acc[j];
        }
    }

    // ---- prefetch phase-B inputs that don't depend on phase A -------------
    const int b  = blockIdx.x;
    const int w0 = sent[b * SLEN + tid];
    const int w1 = sent[b * SLEN + 256 + tid];
    const float bb3 = b3[0], bb4 = b4[0], bb5 = b5[0];

    // ================= device barrier (release/acquire) ====================
    __syncthreads();
    if (tid == 0) {
        __hip_atomic_fetch_add(cnt, 1u, __ATOMIC_RELEASE,
                               __HIP_MEMORY_SCOPE_AGENT);
        while (__hip_atomic_load(cnt, __ATOMIC_ACQUIRE,
                                 __HIP_MEMORY_SCOPE_AGENT) < (unsigned)NSENT)
            __builtin_amdgcn_s_sleep(2);
    }
    __syncthreads();

    // ================= Phase B: finish sentence b ==========================
    {
        const float4* r0p = reinterpret_cast<const float4*>(s + (size_t)w0 * NROW);
        const float4* r1p = reinterpret_cast<const float4*>(s + (size_t)w1 * NROW);
        const float4 sa0 = r0p[0], sb0 = r0p[1], sc0 = r0p[2];
        const float4 sa1 = r1p[0], sb1 = r1p[1], sc1 = r1p[2];

        const int ta = tid, tb = tid + 256;
        s_lds[ 0*SLEN+ta]=sa0.x; s_lds[ 1*SLEN+ta]=sa0.y;
        s_lds[ 2*SLEN+ta]=sa0.z; s_lds[ 3*SLEN+ta]=sa0.w;
        s_lds[ 4*SLEN+ta]=sb0.x; s_lds[ 5*SLEN+ta]=sb0.y;
        s_lds[ 6*SLEN+ta]=sb0.z; s_lds[ 7*SLEN+ta]=sb0.w;
        s_lds[ 8*SLEN+ta]=sc0.x; s_lds[ 9*SLEN+ta]=sc0.y;
        s_lds[10*SLEN+ta]=sc0.z; s_lds[11*SLEN+ta]=sc0.w;
        s_lds[ 0*SLEN+tb]=sa1.x; s_lds[ 1*SLEN+tb]=sa1.y;
        s_lds[ 2*SLEN+tb]=sa1.z; s_lds[ 3*SLEN+tb]=sa1.w;
        s_lds[ 4*SLEN+tb]=sb1.x; s_lds[ 5*SLEN+tb]=sb1.y;
        s_lds[ 6*SLEN+tb]=sb1.z; s_lds[ 7*SLEN+tb]=sb1.w;
        s_lds[ 8*SLEN+tb]=sc1.x; s_lds[ 9*SLEN+tb]=sc1.y;
        s_lds[10*SLEN+tb]=sc1.z; s_lds[11*SLEN+tb]=sc1.w;
        __syncthreads();

        float m3 = -1e30f, m4 = -1e30f, m5 = -1e30f;
        #pragma unroll
        for (int p = 0; p < 2; ++p) {
            const int t = tid + p * 256;
            if (t < SLEN - 2)
                m3 = fmaxf(m3, tanhf(s_lds[0*SLEN + t] + s_lds[1*SLEN + t+1] +
                                     s_lds[2*SLEN + t+2] + bb3));
            if (t < SLEN - 3)
                m4 = fmaxf(m4, tanhf(s_lds[3*SLEN + t] + s_lds[4*SLEN + t+1] +
                                     s_lds[5*SLEN + t+2] + s_lds[6*SLEN + t+3] + bb4));
            if (t < SLEN - 4)
                m5 = fmaxf(m5, tanhf(s_lds[7*SLEN + t] + s_lds[8*SLEN + t+1] +
                                     s_lds[9*SLEN + t+2] + s_lds[10*SLEN + t+3] +
                                     s_lds[11*SLEN + t+4] + bb5));
        }
        #pragma unroll
        for (int off = 32; off; off >>= 1) {
            m3 = fmaxf(m3, __shfl_xor(m3, off));
            m4 = fmaxf(m4, __shfl_xor(m4, off));
            m5 = fmaxf(m5, __shfl_xor(m5, off));
        }
        if (lane == 0) { red[wave][0]=m3; red[wave][1]=m4; red[wave][2]=m5; }
        __syncthreads();

        if (tid == 0) {
            float f3 = red[0][0], f4 = red[0][1], f5 = red[0][2];
            #pragma unroll
            for (int w = 1; w < 4; ++w) {
                f3 = fmaxf(f3, red[w][0]);
                f4 = fmaxf(f4, red[w][1]);
                f5 = fmaxf(f5, red[w][2]);
            }
            float lg[10];
            float mx = -1e30f;
            #pragma unroll
            for (int c = 0; c < 10; ++c) {
                lg[c] = fcb[c] + f3 * fcw[c*3+0] + f4 * fcw[c*3+1]
                               + f5 * fcw[c*3+2];
                mx = fmaxf(mx, lg[c]);
            }
            float ssum = 0.f;
            #pragma unroll
            for (int c = 0; c < 10; ++c) ssum += expf(lg[c] - mx);
            const float lse = logf(ssum);
            #pragma unroll
            for (int c = 0; c < 10; ++c) out[b * 10 + c] = lg[c] - mx - lse;
        }
    }
}

extern "C" void kernel_launch(void* const* d_in, const int* in_sizes, int n_in,
                              void* d_out, int out_size, void* d_ws, size_t ws_size,
                              hipStream_t stream) {
    const int*   sent = (const int*)  d_in[0];
    const float* emb  = (const float*)d_in[1];
    const float* k3   = (const float*)d_in[2];
    const float* b3   = (const float*)d_in[3];
    const float* k4   = (const float*)d_in[4];
    const float* b4   = (const float*)d_in[5];
    const float* k5   = (const float*)d_in[6];
    const float* b5   = (const float*)d_in[7];
    const float* fcw  = (const float*)d_in[8];
    const float* fcb  = (const float*)d_in[9];
    float* out = (float*)d_out;
    float* s   = (float*)d_ws;                                   // 2.4 MB
    unsigned int* cnt = (unsigned int*)((char*)d_ws + CNT_OFF);  // barrier ctr

    hipMemsetAsync(cnt, 0, 64, stream);   // stateless per-call barrier reset
    textcnn_fused<<<NSENT, 256, 0, stream>>>(sent, emb, k3, b3, k4, b4,
                                             k5, b5, fcw, fcb, out, s, cnt);
}

// Round 11
// 36.925 us; speedup vs baseline: 1.3171x; 1.3171x over previous
//
#include <hip/hip_runtime.h>
#include <hip/hip_bf16.h>
#include <math.h>

#define NSENT 256
#define SLEN  512
#define VROWS 50000
#define EDIM  300
#define NROW  12
#define NSTEP 10          // ceil(300/32) K-steps of 16x16x32 MFMA

typedef __attribute__((ext_vector_type(8))) short bf16x8;
typedef __attribute__((ext_vector_type(4))) float f32x4;

static __device__ __forceinline__ short f2bf(float f) {
    __hip_bfloat16 h = __float2bfloat16(f);   // RNE
    short s;
    __builtin_memcpy(&s, &h, sizeof(s));
    return s;
}

// ---------------------------------------------------------------------------
// Kernel A (byte-identical to round 8): vocab scores via bf16 MFMA.
// NOTE: launched TWICE this round as a timing probe (idempotent writes) —
// dur_round11 - dur_round8 = cost(A) + launch overhead.
// ---------------------------------------------------------------------------
__global__ __launch_bounds__(256, 4)
void vocab_scores_mfma(const float* __restrict__ emb,
                       const float* __restrict__ k3,
                       const float* __restrict__ k4,
                       const float* __restrict__ k5,
                       float* __restrict__ s)
{
    __shared__ bf16x8 bfrag_lds[NSTEP * 64];   // 10 KB

    const int tid  = threadIdx.x;
    const int lane = tid & 63;
    const int wave = tid >> 6;      // 0..3
    const int rc   = lane & 15;     // A-row-in-tile / D-col (conv row)
    const int kg   = lane >> 4;     // k-group 0..3

    // ---- build B fragments cooperatively (weights ~14KB, L1/L2-hot) ------
    for (int e = tid; e < NSTEP * 64; e += 256) {
        const int st  = e >> 6;
        const int le  = e & 63;
        const int rce = le & 15;
        const int kge = le >> 4;
        const float* krow = nullptr;
        if      (rce < 3)  krow = k3 + rce * EDIM;
        else if (rce < 7)  krow = k4 + (rce - 3) * EDIM;
        else if (rce < 12) krow = k5 + (rce - 7) * EDIM;
        const int k0 = st * 32 + kge * 8;
        float4 b0 = make_float4(0.f,0.f,0.f,0.f);
        float4 b1 = make_float4(0.f,0.f,0.f,0.f);
        if (krow) {
            if (k0 + 4 <= EDIM) b0 = *reinterpret_cast<const float4*>(krow + k0);
            if (k0 + 8 <= EDIM) b1 = *reinterpret_cast<const float4*>(krow + k0 + 4);
        }
        bf16x8 f;
        f[0]=f2bf(b0.x); f[1]=f2bf(b0.y); f[2]=f2bf(b0.z); f[3]=f2bf(b0.w);
        f[4]=f2bf(b1.x); f[5]=f2bf(b1.y); f[6]=f2bf(b1.z); f[7]=f2bf(b1.w);
        bfrag_lds[e] = f;
    }
    __syncthreads();

    const int vbase = blockIdx.x * 64 + wave * 16;
    const int vrow  = min(vbase + rc, VROWS - 1);    // clamp tail; stores guarded
    const float* arow = emb + (size_t)vrow * EDIM;

    f32x4 acc = {0.f, 0.f, 0.f, 0.f};

    #pragma unroll
    for (int half = 0; half < 2; ++half) {
        // batch 5 K-steps of A loads (10 float4 = 40 VGPR live)
        float4 a0[5], a1[5];
        #pragma unroll
        for (int i = 0; i < 5; ++i) {
            const int k0 = (half * 5 + i) * 32 + kg * 8;
            a0[i] = (k0 + 4 <= EDIM)
                  ? *reinterpret_cast<const float4*>(arow + k0)
                  : make_float4(0.f,0.f,0.f,0.f);
            a1[i] = (k0 + 8 <= EDIM)
                  ? *reinterpret_cast<const float4*>(arow + k0 + 4)
                  : make_float4(0.f,0.f,0.f,0.f);
        }
        #pragma unroll
        for (int i = 0; i < 5; ++i) {
            const int st = half * 5 + i;
            const bf16x8 bf = bfrag_lds[st * 64 + lane];   // ds_read_b128
            bf16x8 af;
            af[0]=f2bf(a0[i].x); af[1]=f2bf(a0[i].y);
            af[2]=f2bf(a0[i].z); af[3]=f2bf(a0[i].w);
            af[4]=f2bf(a1[i].x); af[5]=f2bf(a1[i].y);
            af[6]=f2bf(a1[i].z); af[7]=f2bf(a1[i].w);
            acc = __builtin_amdgcn_mfma_f32_16x16x32_bf16(af, bf, acc, 0, 0, 0);
        }
    }

    // store D: 4 vocab rows per lane-group
    if (rc < NROW) {
        #pragma unroll
        for (int j = 0; j < 4; ++j) {
            const int v = vbase + kg * 4 + j;
            if (v < VROWS) s[(size_t)v * NROW + rc] = acc[j];
        }
    }
}

// ---------------------------------------------------------------------------
// Kernel B (byte-identical to round 8): gather + windows + tanh + max + fc +
// log_softmax. One block (1024 thr) per sentence.
// ---------------------------------------------------------------------------
__global__ __launch_bounds__(1024, 1)
void textcnn_finish(const int*   __restrict__ sent,
                    const float* __restrict__ s,
                    const float* __restrict__ b3,
                    const float* __restrict__ b4,
                    const float* __restrict__ b5,
                    const float* __restrict__ fcw,
                    const float* __restrict__ fcb,
                    float* __restrict__ out)
{
    __shared__ float s_lds[NROW * SLEN];
    __shared__ float red[8][3];

    const int b = blockIdx.x;
    const int t = threadIdx.x;

    auto gather = [&](int token, int j) {
        const int widx = sent[b * SLEN + token];
        const float4 v = reinterpret_cast<const float4*>(s + (size_t)widx * NROW)[j];
        s_lds[(4*j + 0) * SLEN + token] = v.x;
        s_lds[(4*j + 1) * SLEN + token] = v.y;
        s_lds[(4*j + 2) * SLEN + token] = v.z;
        s_lds[(4*j + 3) * SLEN + token] = v.w;
    };

    gather(t & 511, t >> 9);            // j = 0,1 across the 1024 threads
    if (t < SLEN) gather(t, 2);         // j = 2
    __syncthreads();

    if (t < SLEN) {
        const float bb3 = b3[0], bb4 = b4[0], bb5 = b5[0];
        float m3 = -1e30f, m4 = -1e30f, m5 = -1e30f;
        if (t < SLEN - 2)
            m3 = tanhf(s_lds[0*SLEN + t] + s_lds[1*SLEN + t+1] +
                       s_lds[2*SLEN + t+2] + bb3);
        if (t < SLEN - 3)
            m4 = tanhf(s_lds[3*SLEN + t] + s_lds[4*SLEN + t+1] +
                       s_lds[5*SLEN + t+2] + s_lds[6*SLEN + t+3] + bb4);
        if (t < SLEN - 4)
            m5 = tanhf(s_lds[7*SLEN + t] + s_lds[8*SLEN + t+1] +
                       s_lds[9*SLEN + t+2] + s_lds[10*SLEN + t+3] +
                       s_lds[11*SLEN + t+4] + bb5);

        #pragma unroll
        for (int off = 32; off; off >>= 1) {
            m3 = fmaxf(m3, __shfl_xor(m3, off));
            m4 = fmaxf(m4, __shfl_xor(m4, off));
            m5 = fmaxf(m5, __shfl_xor(m5, off));
        }
        if ((t & 63) == 0) {
            const int w = t >> 6;
            red[w][0] = m3; red[w][1] = m4; red[w][2] = m5;
        }
    }
    __syncthreads();

    if (t == 0) {
        float f3 = red[0][0], f4 = red[0][1], f5 = red[0][2];
        #pragma unroll
        for (int w = 1; w < 8; ++w) {
            f3 = fmaxf(f3, red[w][0]);
            f4 = fmaxf(f4, red[w][1]);
            f5 = fmaxf(f5, red[w][2]);
        }
        float lg[10];
        float mx = -1e30f;
        #pragma unroll
        for (int c = 0; c < 10; ++c) {
            lg[c] = fcb[c] + f3 * fcw[c*3+0] + f4 * fcw[c*3+1] + f5 * fcw[c*3+2];
            mx = fmaxf(mx, lg[c]);
        }
        float ssum = 0.f;
        #pragma unroll
        for (int c = 0; c < 10; ++c) ssum += expf(lg[c] - mx);
        const float lse = logf(ssum);
        #pragma unroll
        for (int c = 0; c < 10; ++c) out[b * 10 + c] = lg[c] - mx - lse;
    }
}

extern "C" void kernel_launch(void* const* d_in, const int* in_sizes, int n_in,
                              void* d_out, int out_size, void* d_ws, size_t ws_size,
                              hipStream_t stream) {
    const int*   sent = (const int*)  d_in[0];
    const float* emb  = (const float*)d_in[1];
    const float* k3   = (const float*)d_in[2];
    const float* b3   = (const float*)d_in[3];
    const float* k4   = (const float*)d_in[4];
    const float* b4   = (const float*)d_in[5];
    const float* k5   = (const float*)d_in[6];
    const float* b5   = (const float*)d_in[7];
    const float* fcw  = (const float*)d_in[8];
    const float* fcb  = (const float*)d_in[9];
    float* out = (float*)d_out;
    float* s   = (float*)d_ws;        // VROWS * 12 * 4 B = 2.4 MB

    const int nblk = (VROWS + 63) / 64;   // 782 blocks, 64 rows each
    // TIMING PROBE: A launched twice (idempotent). T11 - T8 = cost(A)+launch.
    vocab_scores_mfma<<<nblk, 256, 0, stream>>>(emb, k3, k4, k5, s);
    vocab_scores_mfma<<<nblk, 256, 0, stream>>>(emb, k3, k4, k5, s);
    textcnn_finish<<<NSENT, 1024, 0, stream>>>(sent, s, b3, b4, b5, fcw, fcb, out);
}

// Round 12
// 25.038 us; speedup vs baseline: 1.9424x; 1.4748x over previous
//
#include <hip/hip_runtime.h>
#include <hip/hip_bf16.h>
#include <math.h>

#define NSENT 256
#define SLEN  512
#define VROWS 50000
#define EDIM  300
#define NROW  12
#define NSTEP 10          // ceil(300/32) K-steps of 16x16x32 MFMA
#define NTILE 3125        // 16-row tiles; 3125*16 = 50000 exact

typedef __attribute__((ext_vector_type(8))) short bf16x8;
typedef __attribute__((ext_vector_type(4))) float f32x4;

static __device__ __forceinline__ short f2bf(float f) {
    __hip_bfloat16 h = __float2bfloat16(f);   // RNE
    short s;
    __builtin_memcpy(&s, &h, sizeof(s));
    return s;
}

// ---------------------------------------------------------------------------
// Kernel A: vocab scores s[v][r] = dot(emb[v], k_r) via bf16 MFMA.
// Round-12 schedule changes (math identical to round 8):
//  - 1024 blocks (4.0/CU exact), tile = global wave id -> tail is +-1 tile
//    (round 8: 782 blocks = 3.05/CU -> ~1 block-time tail on 14 CUs).
//  - half-0 A-loads issued BEFORE the B-frag LDS build (build hides drain);
//    half-1 loads issued before half-0 compute (MFMA hides drain).
// Inactive waves (gw >= 3125) read row 0 and discard -> uniform barriers.
// D layout: col=lane&15 (conv row), row=(lane>>4)*4+j (m89-verified).
// ---------------------------------------------------------------------------
__global__ __launch_bounds__(256, 4)
void vocab_scores_mfma(const float* __restrict__ emb,
                       const float* __restrict__ k3,
                       const float* __restrict__ k4,
                       const float* __restrict__ k5,
                       float* __restrict__ s)
{
    __shared__ bf16x8 bfrag_lds[NSTEP * 64];   // 10.25 KB

    const int tid  = threadIdx.x;
    const int lane = tid & 63;
    const int wave = tid >> 6;      // 0..3
    const int rc   = lane & 15;     // A-row-in-tile / D-col (conv row)
    const int kg   = lane >> 4;     // k-group 0..3

    const int  gw     = blockIdx.x * 4 + wave;   // global wave = tile id
    const bool active = (gw < NTILE);
    const int  vbase  = active ? gw * 16 : 0;    // inactive: dummy row 0
    const float* arow = emb + (size_t)(vbase + rc) * EDIM;

    // ---- issue half-0 A-loads FIRST (k0 <= 152, always in-bounds) --------
    float4 a0[5], a1[5];
    #pragma unroll
    for (int i = 0; i < 5; ++i) {
        const int k0 = i * 32 + kg * 8;
        a0[i] = *reinterpret_cast<const float4*>(arow + k0);
        a1[i] = *reinterpret_cast<const float4*>(arow + k0 + 4);
    }

    // ---- B-frag build overlaps the half-0 load drain ----------------------
    for (int e = tid; e < NSTEP * 64; e += 256) {
        const int st  = e >> 6;
        const int le  = e & 63;
        const int rce = le & 15;
        const int kge = le >> 4;
        const float* krow = nullptr;
        if      (rce < 3)  krow = k3 + rce * EDIM;
        else if (rce < 7)  krow = k4 + (rce - 3) * EDIM;
        else if (rce < 12) krow = k5 + (rce - 7) * EDIM;
        const int k0 = st * 32 + kge * 8;
        float4 b0 = make_float4(0.f,0.f,0.f,0.f);
        float4 b1 = make_float4(0.f,0.f,0.f,0.f);
        if (krow) {
            if (k0 + 4 <= EDIM) b0 = *reinterpret_cast<const float4*>(krow + k0);
            if (k0 + 8 <= EDIM) b1 = *reinterpret_cast<const float4*>(krow + k0 + 4);
        }
        bf16x8 f;
        f[0]=f2bf(b0.x); f[1]=f2bf(b0.y); f[2]=f2bf(b0.z); f[3]=f2bf(b0.w);
        f[4]=f2bf(b1.x); f[5]=f2bf(b1.y); f[6]=f2bf(b1.z); f[7]=f2bf(b1.w);
        bfrag_lds[e] = f;
    }
    __syncthreads();

    // ---- issue half-1 loads (drain hides under half-0 compute) ------------
    float4 c0[5], c1[5];
    #pragma unroll
    for (int i = 0; i < 5; ++i) {
        const int k0 = (5 + i) * 32 + kg * 8;
        c0[i] = (k0 + 4 <= EDIM)
              ? *reinterpret_cast<const float4*>(arow + k0)
              : make_float4(0.f,0.f,0.f,0.f);
        c1[i] = (k0 + 8 <= EDIM)
              ? *reinterpret_cast<const float4*>(arow + k0 + 4)
              : make_float4(0.f,0.f,0.f,0.f);
    }

    // ---- MFMA: half 0 then half 1 -----------------------------------------
    f32x4 acc = {0.f, 0.f, 0.f, 0.f};
    #pragma unroll
    for (int i = 0; i < 5; ++i) {
        const bf16x8 bf = bfrag_lds[i * 64 + lane];    // ds_read_b128
        bf16x8 af;
        af[0]=f2bf(a0[i].x); af[1]=f2bf(a0[i].y);
        af[2]=f2bf(a0[i].z); af[3]=f2bf(a0[i].w);
        af[4]=f2bf(a1[i].x); af[5]=f2bf(a1[i].y);
        af[6]=f2bf(a1[i].z); af[7]=f2bf(a1[i].w);
        acc = __builtin_amdgcn_mfma_f32_16x16x32_bf16(af, bf, acc, 0, 0, 0);
    }
    #pragma unroll
    for (int i = 0; i < 5; ++i) {
        const bf16x8 bf = bfrag_lds[(5 + i) * 64 + lane];
        bf16x8 af;
        af[0]=f2bf(c0[i].x); af[1]=f2bf(c0[i].y);
        af[2]=f2bf(c0[i].z); af[3]=f2bf(c0[i].w);
        af[4]=f2bf(c1[i].x); af[5]=f2bf(c1[i].y);
        af[6]=f2bf(c1[i].z); af[7]=f2bf(c1[i].w);
        acc = __builtin_amdgcn_mfma_f32_16x16x32_bf16(af, bf, acc, 0, 0, 0);
    }

    // ---- store D: 4 vocab rows per lane-group (exact grid, no row guard) --
    if (active && rc < NROW) {
        #pragma unroll
        for (int j = 0; j < 4; ++j)
            s[(size_t)(vbase + kg * 4 + j) * NROW + rc] = acc[j];
    }
}

// ---------------------------------------------------------------------------
// Kernel B (unchanged, round 8): gather 48B/token from score table, then
// windows + tanh + max + fc + log_softmax. One block (1024 thr) per sentence.
// ---------------------------------------------------------------------------
__global__ __launch_bounds__(1024, 1)
void textcnn_finish(const int*   __restrict__ sent,
                    const float* __restrict__ s,
                    const float* __restrict__ b3,
                    const float* __restrict__ b4,
                    const float* __restrict__ b5,
                    const float* __restrict__ fcw,
                    const float* __restrict__ fcb,
                    float* __restrict__ out)
{
    __shared__ float s_lds[NROW * SLEN];
    __shared__ float red[8][3];

    const int b = blockIdx.x;
    const int t = threadIdx.x;

    auto gather = [&](int token, int j) {
        const int widx = sent[b * SLEN + token];
        const float4 v = reinterpret_cast<const float4*>(s + (size_t)widx * NROW)[j];
        s_lds[(4*j + 0) * SLEN + token] = v.x;
        s_lds[(4*j + 1) * SLEN + token] = v.y;
        s_lds[(4*j + 2) * SLEN + token] = v.z;
        s_lds[(4*j + 3) * SLEN + token] = v.w;
    };

    gather(t & 511, t >> 9);            // j = 0,1 across the 1024 threads
    if (t < SLEN) gather(t, 2);         // j = 2
    __syncthreads();

    if (t < SLEN) {
        const float bb3 = b3[0], bb4 = b4[0], bb5 = b5[0];
        float m3 = -1e30f, m4 = -1e30f, m5 = -1e30f;
        if (t < SLEN - 2)
            m3 = tanhf(s_lds[0*SLEN + t] + s_lds[1*SLEN + t+1] +
                       s_lds[2*SLEN + t+2] + bb3);
        if (t < SLEN - 3)
            m4 = tanhf(s_lds[3*SLEN + t] + s_lds[4*SLEN + t+1] +
                       s_lds[5*SLEN + t+2] + s_lds[6*SLEN + t+3] + bb4);
        if (t < SLEN - 4)
            m5 = tanhf(s_lds[7*SLEN + t] + s_lds[8*SLEN + t+1] +
                       s_lds[9*SLEN + t+2] + s_lds[10*SLEN + t+3] +
                       s_lds[11*SLEN + t+4] + bb5);

        #pragma unroll
        for (int off = 32; off; off >>= 1) {
            m3 = fmaxf(m3, __shfl_xor(m3, off));
            m4 = fmaxf(m4, __shfl_xor(m4, off));
            m5 = fmaxf(m5, __shfl_xor(m5, off));
        }
        if ((t & 63) == 0) {
            const int w = t >> 6;
            red[w][0] = m3; red[w][1] = m4; red[w][2] = m5;
        }
    }
    __syncthreads();

    if (t == 0) {
        float f3 = red[0][0], f4 = red[0][1], f5 = red[0][2];
        #pragma unroll
        for (int w = 1; w < 8; ++w) {
            f3 = fmaxf(f3, red[w][0]);
            f4 = fmaxf(f4, red[w][1]);
            f5 = fmaxf(f5, red[w][2]);
        }
        float lg[10];
        float mx = -1e30f;
        #pragma unroll
        for (int c = 0; c < 10; ++c) {
            lg[c] = fcb[c] + f3 * fcw[c*3+0] + f4 * fcw[c*3+1] + f5 * fcw[c*3+2];
            mx = fmaxf(mx, lg[c]);
        }
        float ssum = 0.f;
        #pragma unroll
        for (int c = 0; c < 10; ++c) ssum += expf(lg[c] - mx);
        const float lse = logf(ssum);
        #pragma unroll
        for (int c = 0; c < 10; ++c) out[b * 10 + c] = lg[c] - mx - lse;
    }
}

extern "C" void kernel_launch(void* const* d_in, const int* in_sizes, int n_in,
                              void* d_out, int out_size, void* d_ws, size_t ws_size,
                              hipStream_t stream) {
    const int*   sent = (const int*)  d_in[0];
    const float* emb  = (const float*)d_in[1];
    const float* k3   = (const float*)d_in[2];
    const float* b3   = (const float*)d_in[3];
    const float* k4   = (const float*)d_in[4];
    const float* b4   = (const float*)d_in[5];
    const float* k5   = (const float*)d_in[6];
    const float* b5   = (const float*)d_in[7];
    const float* fcw  = (const float*)d_in[8];
    const float* fcb  = (const float*)d_in[9];
    float* out = (float*)d_out;
    float* s   = (float*)d_ws;        // VROWS * 12 * 4 B = 2.4 MB

    vocab_scores_mfma<<<1024, 256, 0, stream>>>(emb, k3, k4, k5, s);
    textcnn_finish<<<NSENT, 1024, 0, stream>>>(sent, s, b3, b4, b5, fcw, fcb, out);
}